// Round 5
// baseline (643.475 us; speedup 1.0000x reference)
//
#include <hip/hip_runtime.h>
#include <stdint.h>

// ---------------------------------------------------------------------------
// SSL_34857954574989: dense SSM with spectral-norm-scaled K.
// w = S x  =>  w_{t+1} = K11n w_t + gamma*K12n u_t ;  y_t = K21n w_t + gamma*K22n u_t
//
// 5 fused launches (role-split by blockIdx; all roles independent inside a
// launch -> deadlock-free regardless of dispatch order):
//  kA: build_KT(bf16) + conv_w12 + conv_K22 + rec init
//  kB: G = K^T K (MFMA GEMM, 64 blocks, first) || conv_u || w0_matvec
//  kC: 40-step Lanczos on G (32 blocks, first; self-tagged 8B record exchange,
//      one leg/iter; alpha/beta redundant+deterministic; Sturm bisection +
//      scan-coef folded into block 0 tail)
//      || GEMM1 (Bu = u @ K12^T, 2048 blocks)
//      || [split mode] Y2 = u @ K22^T f32 -> d_out (2048 blocks)
//      (both sigma-independent -> hidden under lanczos latency)
//  kD: scan (512 blocks, first) || build_wcat
//  GEMM2: split: y = pre @ (K21 inv)^T + gi*Y2 (K=512, RMW d_out)
//         fallback: y = [pre|u] @ [K21n | gamma*K22n]^T (K=1024)
// Split mode needs Bu (67 MB) in workspace; host guards on ws_size and falls
// back to the round-4 path when it doesn't fit.
// ---------------------------------------------------------------------------

#define LM 40            // Lanczos steps
#define CHUNK 128        // scan chunk length
#define WARM 12          // scan warm-up steps
#define LBLK 32          // lanczos blocks (32 rows each)

typedef float f32x4 __attribute__((ext_vector_type(4)));
typedef __bf16 bf16x8 __attribute__((ext_vector_type(8)));
typedef unsigned int u32;
typedef unsigned long long u64;
typedef unsigned short u16;

static __device__ __forceinline__ u16 f2bf(float f){
  u32 u = __float_as_uint(f);
  u32 r = (u + 0x7fffu + ((u >> 16) & 1u)) >> 16;
  return (u16)r;
}

// K_raw(i,j) evaluated directly (i=row, j=col of the 1024x1024 block matrix)
static __device__ __forceinline__ float kraw_at(int i, int j,
    const float* rho_raw, const float* theta,
    const float* K12, const float* K21, const float* K22){
  if (i < 512){
    if (j < 512){
      if ((i >> 1) != (j >> 1)) return 0.f;
      int p = i >> 1;
      float rho = (1.f / (1.f + expf(-rho_raw[p]))) * 0.999f;
      float c = cosf(theta[p]), s = sinf(theta[p]);
      return ((i & 1) == 0) ? (((j & 1) == 0) ? rho * c : -rho * s)
                            : (((j & 1) == 0) ? rho * s :  rho * c);
    }
    return K12[i * 512 + (j - 512)];
  }
  if (j < 512) return K21[(i - 512) * 512 + j];
  return K22[(i - 512) * 512 + (j - 512)];
}

// ------------------------------------------------------------------ bf16 GEMM
// C[M x N] = A[M x K] bf16 * B[N x K]^T bf16. 128x128 tile, BK=64.
// XCD-partitioned block swizzle; XOR-swizzled LDS layout. Callable from fused
// kernels: g = local block id, ngrid = local grid size.
// MODE 0: plain store (OT = float or u16/bf16).
// MODE 1: f32 RMW accumulate: C = acc + accs[2]*C_old.
static __device__ __forceinline__ void gload16(const u16* g, u16* l){
  __builtin_amdgcn_global_load_lds((const __attribute__((address_space(1))) u32*)g,
                                   (__attribute__((address_space(3))) u32*)l, 16, 0, 0);
}

template <typename OT, int MODE>
static __device__ __forceinline__ void gemm_body(int g, int ngrid,
    const u16* __restrict__ A, int lda, const u16* __restrict__ B, int ldb,
    OT* __restrict__ C, int ldc, int K, int ntn, const float* accs){
  __shared__ u16 As[128 * 64];
  __shared__ u16 Bs[128 * 64];
  int xcd = g & 7, local = g >> 3;
  int mper = (ngrid >> 3) / ntn;              // m-tiles per xcd
  int bn = local % ntn;
  int bm = xcd * mper + local / ntn;
  int t = threadIdx.x, lane = t & 63, wave = t >> 6;
  int lrow = t >> 3;                          // 0..31
  int swz = (((t & 7) ^ (lrow & 7)) << 3);    // XOR-swizzled col offset (elems)
  const u16* Ag = A + (size_t)(bm * 128 + lrow) * lda + swz;
  const u16* Bg = B + (size_t)(bn * 128 + lrow) * ldb + swz;
  u16* Asd = As + t * 8;
  u16* Bsd = Bs + t * 8;
  f32x4 acc[4][4];
  #pragma unroll
  for (int mi = 0; mi < 4; ++mi)
    #pragma unroll
    for (int ni = 0; ni < 4; ++ni) acc[mi][ni] = (f32x4){0.f, 0.f, 0.f, 0.f};
  int wm = (wave & 1) << 6, wn = (wave >> 1) << 6;
  int fr = lane & 15, cbb = lane >> 4;
  for (int kt = 0; kt < K; kt += 64){
    __syncthreads();
    #pragma unroll
    for (int r = 0; r < 4; ++r){
      gload16(Ag + (size_t)(r * 32) * lda + kt, Asd + r * 2048);
      gload16(Bg + (size_t)(r * 32) * ldb + kt, Bsd + r * 2048);
    }
    __syncthreads();
    #pragma unroll
    for (int kk = 0; kk < 2; ++kk){
      bf16x8 af[4], bfr[4];
      #pragma unroll
      for (int mi = 0; mi < 4; ++mi){
        int row = wm + mi * 16 + fr;
        int pcb = ((kk << 2) + cbb) ^ (fr & 7);
        af[mi] = *(const bf16x8*)(As + row * 64 + pcb * 8);
      }
      #pragma unroll
      for (int ni = 0; ni < 4; ++ni){
        int row = wn + ni * 16 + fr;
        int pcb = ((kk << 2) + cbb) ^ (fr & 7);
        bfr[ni] = *(const bf16x8*)(Bs + row * 64 + pcb * 8);
      }
      #pragma unroll
      for (int mi = 0; mi < 4; ++mi)
        #pragma unroll
        for (int ni = 0; ni < 4; ++ni)
          acc[mi][ni] = __builtin_amdgcn_mfma_f32_16x16x32_bf16(af[mi], bfr[ni], acc[mi][ni], 0, 0, 0);
    }
  }
  float s = 0.f;
  if constexpr (MODE == 1) s = accs[2];
  int rq = lane >> 4;
  #pragma unroll
  for (int mi = 0; mi < 4; ++mi)
    #pragma unroll
    for (int ni = 0; ni < 4; ++ni){
      size_t base = (size_t)(bm * 128 + wm + mi * 16 + rq * 4) * ldc
                  + (size_t)(bn * 128 + wn + ni * 16 + fr);
      #pragma unroll
      for (int r = 0; r < 4; ++r){
        size_t idx = base + (size_t)r * ldc;
        if constexpr (MODE == 1){
          float old = C[idx];
          C[idx] = acc[mi][ni][r] + s * old;
        } else if constexpr (sizeof(OT) == 4){
          C[idx] = acc[mi][ni][r];
        } else {
          C[idx] = (OT)f2bf(acc[mi][ni][r]);
        }
      }
    }
}

// --------------------------- kA: KT + conv_w12 + conv_K22 + rec init
__global__ __launch_bounds__(256) void kA(const float* rho_raw, const float* theta,
    const float* K12, const float* K21, const float* K22, u16* KTbf,
    const float4* k12_4, u16* W12, const float4* k22_4, u16* K22bf, u64* rec){
  int blk = blockIdx.x;
  if (blk < 4096){
    int idx = blk * 256 + threadIdx.x;           // KT output idx
    int j = idx >> 10, i = idx & 1023;           // KT row j, col i
    KTbf[idx] = f2bf(kraw_at(i, j, rho_raw, theta, K12, K21, K22));
  } else if (blk < 4096 + 256){
    long g = (long)(blk - 4096) * 256 + threadIdx.x; // 65536 total
    float4 v = k12_4[g];
    u32 lo = (u32)f2bf(v.x) | ((u32)f2bf(v.y) << 16);
    u32 hi = (u32)f2bf(v.z) | ((u32)f2bf(v.w) << 16);
    ((uint2*)W12)[g] = make_uint2(lo, hi);
  } else if (blk < 4096 + 512){
    long g = (long)(blk - 4352) * 256 + threadIdx.x; // 65536 total
    float4 v = k22_4[g];
    u32 lo = (u32)f2bf(v.x) | ((u32)f2bf(v.y) << 16);
    u32 hi = (u32)f2bf(v.z) | ((u32)f2bf(v.w) << 16);
    ((uint2*)K22bf)[g] = make_uint2(lo, hi);
  } else {
    for (int i = threadIdx.x; i < 2048; i += 256) rec[i] = 0ull;
  }
}

// -------------------------------------------- kB: Ggemm || conv_u || w0
__global__ __launch_bounds__(256) void kB(const u16* KTbf, float* G,
    const float4* u4, u16* X, const float* S, const float* state, float* w0){
  int blk = blockIdx.x;
  if (blk < 64){
    gemm_body<float, 0>(blk, 64, KTbf, 1024, KTbf, 1024, G, 1024, 1024, 8, nullptr);
  } else if (blk < 64 + 32768){
    long g = (long)(blk - 64) * 256 + threadIdx.x;   // 8388608 total
    float4 v = u4[g];
    int h4 = (int)(g & 127);
    long row = g >> 7;
    u16* dst = X + row * 1024 + 512 + h4 * 4;
    u32 lo = (u32)f2bf(v.x) | ((u32)f2bf(v.y) << 16);
    u32 hi = (u32)f2bf(v.z) | ((u32)f2bf(v.w) << 16);
    *((uint2*)dst) = make_uint2(lo, hi);
  } else {
    int idx = (blk - 32832) * 256 + threadIdx.x;     // 8192 total
    int b = idx >> 9, n = idx & 511;
    const float* sr = S + n * 512;
    const float* st = state + b * 512;
    float acc = 0.f;
    for (int m2 = 0; m2 < 512; ++m2) acc += sr[m2] * st[m2];
    w0[idx] = acc;
  }
}

// ------- kC: lanczos (0..31) || GEMM1 (32..2079) || [split] Y2 (2080..4127)
// Lanczos block b owns rows [32b,32b+32) of G in VGPRs. Per iteration:
// publish 32 y-values as self-tagged 8B records {f32,iter} (one agent leg),
// poll all 1024, then redundantly+deterministically compute alpha,w,beta in
// every block (identical FP order => identical results). Block 0 keeps
// alpha/beta^2 in LDS and runs Sturm bisection + coef at the end.
__global__ __launch_bounds__(256, 1) void kC(const float* __restrict__ G,
    u64* rec, const float* rho_raw, const float* theta, const float* log_gamma,
    float* scal, float2* coef,
    const u16* Xu, const u16* W12, u16* Bu, const u16* K22bf, float* Y2){
  if (blockIdx.x >= LBLK + 2048){
    // Y2 = u_bf16 @ K22^T (f32, raw), straight into d_out
    gemm_body<float, 0>(blockIdx.x - LBLK - 2048, 2048, Xu, 1024, K22bf, 512,
                        Y2, 512, 512, 4, nullptr);
    return;
  }
  if (blockIdx.x >= LBLK){
    gemm_body<u16, 0>(blockIdx.x - LBLK, 2048, Xu, 1024, W12, 512, Bu, 512,
                      512, 4, nullptr);
    return;
  }
  __shared__ __align__(16) float vl[1024];  // raw v_{j-1} (full vector)
  __shared__ float red[8];
  __shared__ double sa[LM], sb2[LM + 1];
  __shared__ float sh_inv;
  int t = threadIdx.x, wave = t >> 6, lane = t & 63;
  int row0 = blockIdx.x * 32;

  // ---- my 32 G rows -> registers. wave w owns rows 8w..8w+7; lane l holds
  // floats [4l+256*i2, +4) of each row.
  f32x4 greg[8][4];
  {
    const float* gbase = G + (size_t)(row0 + wave * 8) * 1024 + lane * 4;
    #pragma unroll
    for (int rr = 0; rr < 8; ++rr)
      #pragma unroll
      for (int i2 = 0; i2 < 4; ++i2)
        greg[rr][i2] = *(const f32x4*)(gbase + (size_t)rr * 1024 + i2 * 256);
  }

  // ---- v0 raw + deterministic redundant norm (identical in every block)
  float vprevreg[4] = {0.f, 0.f, 0.f, 0.f};
  float n2tot;
  {
    float s = 0.f;
    #pragma unroll
    for (int k = 0; k < 4; ++k){
      int i = t + 256 * k;
      float v = sinf(0.613f * (float)i + 0.271f) + 0.3f * sinf(0.0247f * (float)i + 1.3f);
      vl[i] = v;
      s += v * v;
    }
    #pragma unroll
    for (int off = 32; off; off >>= 1) s += __shfl_down(s, off);
    if (lane == 0) red[wave] = s;
    __syncthreads();
    n2tot = (red[0] + red[1]) + (red[2] + red[3]);
  }
  float scl = 1.f / sqrtf(n2tot);      // 1/beta_0
  float betacoef = 0.f;                // no v_prev term at j=1
  if (t == 0) sb2[0] = 0.0;

  for (int j = 1; j <= LM; ++j){
    u64* rb = rec + ((j & 1) ? 0 : 1024);   // double buffer by parity
    // ---- y_raw(my rows) = G * v_raw; butterfly reduce so lanes 0..7 hold
    // their row's value; publish self-tagged records.
    {
      f32x4 vreg[4];
      #pragma unroll
      for (int i2 = 0; i2 < 4; ++i2)
        vreg[i2] = *((const f32x4*)vl + lane + 64 * i2);
      u64 myrec = 0ull;
      #pragma unroll
      for (int rr = 0; rr < 8; ++rr){
        float s = 0.f;
        #pragma unroll
        for (int i2 = 0; i2 < 4; ++i2){
          f32x4 g = greg[rr][i2], v = vreg[i2];
          s += g[0] * v[0] + g[1] * v[1] + g[2] * v[2] + g[3] * v[3];
        }
        #pragma unroll
        for (int off = 32; off; off >>= 1) s += __shfl_xor(s, off);
        if (lane == rr)
          myrec = ((u64)(u32)j << 32) | (u64)__float_as_uint(s);
      }
      if (lane < 8)
        __hip_atomic_store(&rb[row0 + wave * 8 + lane], myrec,
                           __ATOMIC_RELAXED, __HIP_MEMORY_SCOPE_AGENT);
    }

    // ---- poll full y: tag==j => payload valid. 4 loads kept in flight.
    float yr[4], vr[4];
    {
      u64 r0, r1, r2, r3;
      bool done = false;
      while (!done){
        r0 = __hip_atomic_load(&rb[t        ], __ATOMIC_RELAXED, __HIP_MEMORY_SCOPE_AGENT);
        r1 = __hip_atomic_load(&rb[t +  256 ], __ATOMIC_RELAXED, __HIP_MEMORY_SCOPE_AGENT);
        r2 = __hip_atomic_load(&rb[t +  512 ], __ATOMIC_RELAXED, __HIP_MEMORY_SCOPE_AGENT);
        r3 = __hip_atomic_load(&rb[t +  768 ], __ATOMIC_RELAXED, __HIP_MEMORY_SCOPE_AGENT);
        done = ((u32)(r0 >> 32) == (u32)j) && ((u32)(r1 >> 32) == (u32)j)
            && ((u32)(r2 >> 32) == (u32)j) && ((u32)(r3 >> 32) == (u32)j);
        if (!done) __builtin_amdgcn_s_sleep(1);
      }
      yr[0] = __uint_as_float((u32)r0); yr[1] = __uint_as_float((u32)r1);
      yr[2] = __uint_as_float((u32)r2); yr[3] = __uint_as_float((u32)r3);
      #pragma unroll
      for (int k = 0; k < 4; ++k) vr[k] = vl[t + 256 * k];
    }

    // ---- redundant deterministic alpha: dot = v_raw^T y_raw
    float dotp = 0.f;
    #pragma unroll
    for (int k = 0; k < 4; ++k) dotp += vr[k] * yr[k];
    #pragma unroll
    for (int off = 32; off; off >>= 1) dotp += __shfl_down(dotp, off);
    if (lane == 0) red[wave] = dotp;
    __syncthreads();
    float dot = (red[0] + red[1]) + (red[2] + red[3]);
    float alpha_f = dot * scl * scl;

    // ---- w = scl*y - alpha*vhat - beta*vprevhat (full vector, redundant)
    float n2 = 0.f;
    #pragma unroll
    for (int k = 0; k < 4; ++k){
      float vh = vr[k] * scl;
      float wv = yr[k] * scl - alpha_f * vh - betacoef * vprevreg[k];
      vprevreg[k] = vh;
      vl[t + 256 * k] = wv;            // raw next v
      n2 += wv * wv;
    }
    #pragma unroll
    for (int off = 32; off; off >>= 1) n2 += __shfl_down(n2, off);
    if (lane == 0) red[4 + wave] = n2;
    __syncthreads();                    // also orders vl[] writes vs next matvec
    n2tot = (red[4] + red[5]) + (red[6] + red[7]);
    if (n2tot < 1e-30f) n2tot = 1e-30f;

    if (t == 0){ sa[j - 1] = (double)alpha_f; sb2[j] = (double)n2tot; }
    betacoef = sqrtf(n2tot);
    scl = 1.f / betacoef;
  }

  // ---- block 0 tail: Sturm bisection for lambda_max(T), sigma, scan coef
  if (blockIdx.x != 0) return;
  __syncthreads();
  if (t < 64){
    int lane2 = t;
    double lo = sa[0], hi = sa[0], bmax = 0.0;
    for (int i = 0; i < LM; ++i){
      if (sa[i] > lo) lo = sa[i];
      double bl = (i > 0) ? sqrt(fmax(sb2[i], 0.0)) : 0.0;
      double br = (i < LM - 1) ? sqrt(fmax(sb2[i + 1], 0.0)) : 0.0;
      double g = sa[i] + bl + br;
      if (g > hi) hi = g;
      if (i < LM - 1 && sb2[i + 1] > bmax) bmax = sb2[i + 1];
    }
    hi = hi + 1e-6 * fabs(hi) + 1e-20;
    lo = lo - 1e-6 * fabs(lo) - 1e-20;
    double pivmin = 1e-30 * bmax + 1e-300;
    for (int round = 0; round < 6; ++round){
      double x = lo + (hi - lo) * ((double)(lane2 + 1) / 65.0);
      double d = sa[0] - x; int cnt = (d < 0.0);
      for (int i = 1; i < LM; ++i){
        if (fabs(d) < pivmin) d = -pivmin;
        d = (sa[i] - x) - sb2[i] / d;
        cnt += (d < 0.0);
      }
      unsigned long long mk = __ballot(cnt >= LM);
      int bpos = (mk == 0ULL) ? 64 : (__ffsll((unsigned long long)mk) - 1);
      double xlo = __shfl(x, (bpos == 0) ? 0 : bpos - 1);
      double xhi = __shfl(x, (bpos == 64) ? 63 : bpos);
      double nlo = (bpos == 0) ? lo : xlo;
      double nhi = (bpos == 64) ? hi : xhi;
      lo = nlo; hi = nhi;
    }
    if (lane2 == 0){
      double lam = 0.5 * (lo + hi);
      double sig = (lam > 0.0) ? sqrt(lam) : 0.0;
      if (sig < 1e-5) sig = 1e-5;
      double spp = sig + 0.002;
      float inv = (float)(1.0 / spp);
      float g = expf(log_gamma[0]);
      scal[0] = inv; scal[1] = g; scal[2] = g * inv;
      sh_inv = inv;
    }
  }
  __syncthreads();
  float inv = sh_inv;
  float rho = (1.f / (1.f + expf(-rho_raw[t]))) * 0.999f;
  float c = cosf(theta[t]), s = sinf(theta[t]);
  coef[t] = make_float2(rho * c * inv, rho * s * inv);
}

// ------------------------------ kD: scan (blocks 0..511) || wcat (512..)
// wcols = 512 (split: K21*inv only) or 1024 (fallback: [K21*inv | K22*gi])
__global__ __launch_bounds__(256) void kD(const u32* Bu, const float2* coef,
    const float* w0, const float* scal, u16* X,
    const float* K21, const float* K22, u16* W, int wcols){
  int blk = blockIdx.x;
  if (blk >= 512){
    int idx = (blk - 512) * 256 + threadIdx.x;
    float inv = scal[0], gi2 = scal[2];
    if (wcols == 1024){
      int o = idx >> 10, c = idx & 1023;
      float v = (c < 512) ? K21[o * 512 + c] * inv : K22[o * 512 + (c - 512)] * gi2;
      W[idx] = f2bf(v);
    } else {
      int o = idx >> 9, c = idx & 511;
      W[idx] = f2bf(K21[o * 512 + c] * inv);
    }
    return;
  }
  int b = blk >> 5;                  // 16 batches
  int c = blk & 31;                  // 32 chunks of 128
  int p = threadIdx.x;               // 256 pairs
  float2 ab = coef[p];
  float gi = scal[2];
  int t0 = c * CHUNK;
  float wx, wy; int t;
  if (c == 0){ wx = w0[b * 512 + 2 * p]; wy = w0[b * 512 + 2 * p + 1]; t = 0; }
  else { wx = 0.f; wy = 0.f; t = t0 - WARM; }
  const u32* bub = Bu + (size_t)b * 4096 * 256;
  u16* xb = X + (size_t)b * 4096 * 1024;
  for (; t < t0; ++t){
    u32 v = bub[(size_t)t * 256 + p];
    float bx = __uint_as_float(v << 16);
    float by = __uint_as_float(v & 0xffff0000u);
    float nx = ab.x * wx - ab.y * wy + gi * bx;
    float ny = ab.y * wx + ab.x * wy + gi * by;
    wx = nx; wy = ny;
  }
  for (; t < t0 + CHUNK; ++t){
    u32 pk = (u32)f2bf(wx) | ((u32)f2bf(wy) << 16);
    *(u32*)(xb + (size_t)t * 1024 + 2 * p) = pk;
    u32 v = bub[(size_t)t * 256 + p];
    float bx = __uint_as_float(v << 16);
    float by = __uint_as_float(v & 0xffff0000u);
    float nx = ab.x * wx - ab.y * wy + gi * bx;
    float ny = ab.y * wx + ab.x * wy + gi * by;
    wx = nx; wy = ny;
  }
}

// standalone GEMM wrapper (GEMM2 variants)
template <typename OT, int MODE>
__global__ __launch_bounds__(256) void gemm_nt(const u16* __restrict__ A, int lda,
    const u16* __restrict__ B, int ldb, OT* __restrict__ C, int ldc, int K,
    int ntn, const float* accs){
  gemm_body<OT, MODE>(blockIdx.x, gridDim.x, A, lda, B, ldb, C, ldc, K, ntn, accs);
}

// ------------------------------------------------------------------- launcher
extern "C" void kernel_launch(void* const* d_in, const int* in_sizes, int n_in,
                              void* d_out, int out_size, void* d_ws, size_t ws_size,
                              hipStream_t stream){
  const float* u        = (const float*)d_in[0];
  const float* state    = (const float*)d_in[1];
  const float* S        = (const float*)d_in[2];
  const float* rho_raw  = (const float*)d_in[3];
  const float* theta    = (const float*)d_in[4];
  const float* K12      = (const float*)d_in[5];
  const float* K21      = (const float*)d_in[6];
  const float* K22      = (const float*)d_in[7];
  const float* log_gamma= (const float*)d_in[8];

  char* w = (char*)d_ws;
  size_t off = 0;
  auto alloc = [&](size_t bytes)->void*{
    void* p = w + off;
    off = (off + bytes + 255) & ~(size_t)255;
    return p;
  };
  u64*    rec   = (u64*)alloc(2048 * 8);       // 2 x 1024 self-tagged records
  float*  scal  = (float*)alloc(64);
  float2* coef  = (float2*)alloc(256 * 8);
  float*  w0    = (float*)alloc(16 * 512 * 4);
  u16*    KTbf  = (u16*)alloc((size_t)1024 * 1024 * 2);
  float*  G     = (float*)alloc((size_t)1024 * 1024 * 4);
  u16*    W12   = (u16*)alloc((size_t)512 * 512 * 2);
  u16*    K22bf = (u16*)alloc((size_t)512 * 512 * 2);
  u16*    Wcat  = (u16*)alloc((size_t)512 * 1024 * 2);
  u16*    Xb    = (u16*)alloc((size_t)65536 * 1024 * 2);
  u16*    BuWs  = (u16*)alloc((size_t)65536 * 512 * 2);   // split-mode Bu
  bool split = (off <= ws_size);
  // split: Bu in ws, Y2 (f32, raw u@K22^T) in d_out, GEMM2 K=512 RMW.
  // fallback (ws too small): Bu aliases d_out, GEMM2 K=1024 (round-4 path).
  u16*    Bu    = split ? BuWs : (u16*)d_out;

  // kA: KT (4096) + conv_w12 (256) + conv_K22 (256) + rec init (1)
  kA<<<4609, 256, 0, stream>>>(rho_raw, theta, K12, K21, K22, KTbf,
                               (const float4*)K12, W12,
                               (const float4*)K22, K22bf, rec);
  // kB: G = KT @ KT^T (64, first) || conv_u (32768) || w0 (32)
  kB<<<32864, 256, 0, stream>>>(KTbf, G, (const float4*)u, Xb, S, state, w0);
  // kC: lanczos+finalize (32, first) || GEMM1 (2048) || [split] Y2 (2048)
  kC<<<LBLK + 2048 + (split ? 2048 : 0), 256, 0, stream>>>(
      G, rec, rho_raw, theta, log_gamma, scal, coef,
      Xb + 512, W12, Bu, K22bf, (float*)d_out);
  // kD: scan (512, first) || build_wcat
  kD<<<512 + (split ? 1024 : 2048), 256, 0, stream>>>(
      (const u32*)Bu, coef, w0, scal, Xb, K21, K22, Wcat, split ? 512 : 1024);
  if (split){
    // GEMM2: y = pre @ (K21*inv)^T + gi * Y2   (K=512, RMW d_out)
    gemm_nt<float, 1><<<2048, 256, 0, stream>>>(Xb, 1024, Wcat, 512,
                                                (float*)d_out, 512, 512, 4, scal);
  } else {
    // GEMM2: y = [pre|u] @ [K21n | gamma*K22n]^T  (K=1024)
    gemm_nt<float, 0><<<2048, 256, 0, stream>>>(Xb, 1024, Wcat, 1024,
                                                (float*)d_out, 512, 1024, 4, nullptr);
  }
}

// Round 6
// 563.485 us; speedup vs baseline: 1.1420x; 1.1420x over previous
//
#include <hip/hip_runtime.h>
#include <stdint.h>

// ---------------------------------------------------------------------------
// SSL_34857954574989: dense SSM with spectral-norm-scaled K.
// w = S x  =>  w_{t+1} = K11n w_t + gamma*K12n u_t ;  y_t = K21n w_t + gamma*K22n u_t
//
// Fused launches (role-split by blockIdx; roles independent inside a launch
// -> deadlock-free regardless of dispatch order):
//  kA: build_KT(bf16) + conv_w12 + conv_K22 + rec init
//  kB: G = K^T K (MFMA GEMM, 64 blocks, first) || conv_u || w0_matvec
//  kC: 40-step Lanczos on G (32 blocks, first; self-tagged 8B record exchange,
//      one leg/iter; alpha/beta redundant+deterministic; Sturm + coef in
//      block 0 tail)
//      || GEMM1 (Bu = u @ K12^T, 2048 blocks)
//      || [split] Y2 = bf16(u @ K22^T) -> ws (2048 blocks)
//      (both sigma-independent -> hidden under lanczos latency).
//      All GEMM roles share ONE 32KB LDS buffer (single instantiation).
//  kD: scan (512 blocks, first) || build_wcat
//  GEMM2 split: y = pre @ (K21 inv)^T + gi*Y2 (K=512; old-loads hoisted
//               before stores in epilogue)
//        fallback: y = [pre|u] @ [K21n | gamma*K22n]^T (K=1024)
// Split needs Bu(67MB)+Y2(67MB) in ws; host guards on ws_size and falls back
// to the round-4 path when they don't fit.
// ---------------------------------------------------------------------------

#define LM 40            // Lanczos steps
#define CHUNK 128        // scan chunk length
#define WARM 12          // scan warm-up steps
#define LBLK 32          // lanczos blocks (32 rows each)

typedef float f32x4 __attribute__((ext_vector_type(4)));
typedef __bf16 bf16x8 __attribute__((ext_vector_type(8)));
typedef unsigned int u32;
typedef unsigned long long u64;
typedef unsigned short u16;

static __device__ __forceinline__ u16 f2bf(float f){
  u32 u = __float_as_uint(f);
  u32 r = (u + 0x7fffu + ((u >> 16) & 1u)) >> 16;
  return (u16)r;
}
static __device__ __forceinline__ float bf2f(u16 v){
  return __uint_as_float(((u32)v) << 16);
}

// K_raw(i,j) evaluated directly (i=row, j=col of the 1024x1024 block matrix)
static __device__ __forceinline__ float kraw_at(int i, int j,
    const float* rho_raw, const float* theta,
    const float* K12, const float* K21, const float* K22){
  if (i < 512){
    if (j < 512){
      if ((i >> 1) != (j >> 1)) return 0.f;
      int p = i >> 1;
      float rho = (1.f / (1.f + expf(-rho_raw[p]))) * 0.999f;
      float c = cosf(theta[p]), s = sinf(theta[p]);
      return ((i & 1) == 0) ? (((j & 1) == 0) ? rho * c : -rho * s)
                            : (((j & 1) == 0) ? rho * s :  rho * c);
    }
    return K12[i * 512 + (j - 512)];
  }
  if (j < 512) return K21[(i - 512) * 512 + j];
  return K22[(i - 512) * 512 + (j - 512)];
}

// ------------------------------------------------------------------ bf16 GEMM
// C[M x N] = A[M x K] bf16 * B[N x K]^T bf16. 128x128 tile, BK=64.
// XCD-partitioned block swizzle; XOR-swizzled LDS layout. LDS buffers are
// caller-provided (32 KB total) so multiple roles in one kernel share one
// allocation. MODE 0: plain store. MODE 1: C = acc + accs[2]*bf2f(Y2[idx]),
// with the 16 old-loads per mi-row hoisted before any store.
static __device__ __forceinline__ void gload16(const u16* g, u16* l){
  __builtin_amdgcn_global_load_lds((const __attribute__((address_space(1))) u32*)g,
                                   (__attribute__((address_space(3))) u32*)l, 16, 0, 0);
}

template <typename OT, int MODE>
static __device__ __forceinline__ void gemm_body(int g, int ngrid,
    const u16* __restrict__ A, int lda, const u16* __restrict__ B, int ldb,
    OT* __restrict__ C, int ldc, int K, int ntn, const float* accs,
    const u16* __restrict__ Y2, u16* As, u16* Bs){
  int xcd = g & 7, local = g >> 3;
  int mper = (ngrid >> 3) / ntn;              // m-tiles per xcd
  int bn = local % ntn;
  int bm = xcd * mper + local / ntn;
  int t = threadIdx.x, lane = t & 63, wave = t >> 6;
  int lrow = t >> 3;                          // 0..31
  int swz = (((t & 7) ^ (lrow & 7)) << 3);    // XOR-swizzled col offset (elems)
  const u16* Ag = A + (size_t)(bm * 128 + lrow) * lda + swz;
  const u16* Bg = B + (size_t)(bn * 128 + lrow) * ldb + swz;
  u16* Asd = As + t * 8;
  u16* Bsd = Bs + t * 8;
  f32x4 acc[4][4];
  #pragma unroll
  for (int mi = 0; mi < 4; ++mi)
    #pragma unroll
    for (int ni = 0; ni < 4; ++ni) acc[mi][ni] = (f32x4){0.f, 0.f, 0.f, 0.f};
  int wm = (wave & 1) << 6, wn = (wave >> 1) << 6;
  int fr = lane & 15, cbb = lane >> 4;
  for (int kt = 0; kt < K; kt += 64){
    __syncthreads();
    #pragma unroll
    for (int r = 0; r < 4; ++r){
      gload16(Ag + (size_t)(r * 32) * lda + kt, Asd + r * 2048);
      gload16(Bg + (size_t)(r * 32) * ldb + kt, Bsd + r * 2048);
    }
    __syncthreads();
    #pragma unroll
    for (int kk = 0; kk < 2; ++kk){
      bf16x8 af[4], bfr[4];
      #pragma unroll
      for (int mi = 0; mi < 4; ++mi){
        int row = wm + mi * 16 + fr;
        int pcb = ((kk << 2) + cbb) ^ (fr & 7);
        af[mi] = *(const bf16x8*)(As + row * 64 + pcb * 8);
      }
      #pragma unroll
      for (int ni = 0; ni < 4; ++ni){
        int row = wn + ni * 16 + fr;
        int pcb = ((kk << 2) + cbb) ^ (fr & 7);
        bfr[ni] = *(const bf16x8*)(Bs + row * 64 + pcb * 8);
      }
      #pragma unroll
      for (int mi = 0; mi < 4; ++mi)
        #pragma unroll
        for (int ni = 0; ni < 4; ++ni)
          acc[mi][ni] = __builtin_amdgcn_mfma_f32_16x16x32_bf16(af[mi], bfr[ni], acc[mi][ni], 0, 0, 0);
    }
  }
  int rq = lane >> 4;
  if constexpr (MODE == 1){
    float s = accs[2];
    #pragma unroll
    for (int mi = 0; mi < 4; ++mi){
      // hoist all 16 old-loads of this mi-row before any store (keeps the
      // loads pipelined instead of serialized against stores)
      float oldv[16];
      #pragma unroll
      for (int ni = 0; ni < 4; ++ni){
        size_t base = (size_t)(bm * 128 + wm + mi * 16 + rq * 4) * ldc
                    + (size_t)(bn * 128 + wn + ni * 16 + fr);
        #pragma unroll
        for (int r = 0; r < 4; ++r)
          oldv[ni * 4 + r] = bf2f(Y2[base + (size_t)r * ldc]);
      }
      #pragma unroll
      for (int ni = 0; ni < 4; ++ni){
        size_t base = (size_t)(bm * 128 + wm + mi * 16 + rq * 4) * ldc
                    + (size_t)(bn * 128 + wn + ni * 16 + fr);
        #pragma unroll
        for (int r = 0; r < 4; ++r)
          C[base + (size_t)r * ldc] = acc[mi][ni][r] + s * oldv[ni * 4 + r];
      }
    }
  } else {
    #pragma unroll
    for (int mi = 0; mi < 4; ++mi)
      #pragma unroll
      for (int ni = 0; ni < 4; ++ni){
        size_t base = (size_t)(bm * 128 + wm + mi * 16 + rq * 4) * ldc
                    + (size_t)(bn * 128 + wn + ni * 16 + fr);
        #pragma unroll
        for (int r = 0; r < 4; ++r){
          if constexpr (sizeof(OT) == 4) C[base + (size_t)r * ldc] = acc[mi][ni][r];
          else                           C[base + (size_t)r * ldc] = (OT)f2bf(acc[mi][ni][r]);
        }
      }
  }
}

// --------------------------- kA: KT + conv_w12 + conv_K22 + rec init
__global__ __launch_bounds__(256) void kA(const float* rho_raw, const float* theta,
    const float* K12, const float* K21, const float* K22, u16* KTbf,
    const float4* k12_4, u16* W12, const float4* k22_4, u16* K22bf, u64* rec){
  int blk = blockIdx.x;
  if (blk < 4096){
    int idx = blk * 256 + threadIdx.x;           // KT output idx
    int j = idx >> 10, i = idx & 1023;           // KT row j, col i
    KTbf[idx] = f2bf(kraw_at(i, j, rho_raw, theta, K12, K21, K22));
  } else if (blk < 4096 + 256){
    long g = (long)(blk - 4096) * 256 + threadIdx.x; // 65536 total
    float4 v = k12_4[g];
    u32 lo = (u32)f2bf(v.x) | ((u32)f2bf(v.y) << 16);
    u32 hi = (u32)f2bf(v.z) | ((u32)f2bf(v.w) << 16);
    ((uint2*)W12)[g] = make_uint2(lo, hi);
  } else if (blk < 4096 + 512){
    long g = (long)(blk - 4352) * 256 + threadIdx.x; // 65536 total
    float4 v = k22_4[g];
    u32 lo = (u32)f2bf(v.x) | ((u32)f2bf(v.y) << 16);
    u32 hi = (u32)f2bf(v.z) | ((u32)f2bf(v.w) << 16);
    ((uint2*)K22bf)[g] = make_uint2(lo, hi);
  } else {
    for (int i = threadIdx.x; i < 2048; i += 256) rec[i] = 0ull;
  }
}

// -------------------------------------------- kB: Ggemm || conv_u || w0
__global__ __launch_bounds__(256) void kB(const u16* KTbf, float* G,
    const float4* u4, u16* X, const float* S, const float* state, float* w0){
  __shared__ __align__(16) u16 smA[128 * 64];
  __shared__ __align__(16) u16 smB[128 * 64];
  int blk = blockIdx.x;
  if (blk < 64){
    gemm_body<float, 0>(blk, 64, KTbf, 1024, KTbf, 1024, G, 1024, 1024, 8,
                        nullptr, nullptr, smA, smB);
  } else if (blk < 64 + 32768){
    long g = (long)(blk - 64) * 256 + threadIdx.x;   // 8388608 total
    float4 v = u4[g];
    int h4 = (int)(g & 127);
    long row = g >> 7;
    u16* dst = X + row * 1024 + 512 + h4 * 4;
    u32 lo = (u32)f2bf(v.x) | ((u32)f2bf(v.y) << 16);
    u32 hi = (u32)f2bf(v.z) | ((u32)f2bf(v.w) << 16);
    *((uint2*)dst) = make_uint2(lo, hi);
  } else {
    int idx = (blk - 32832) * 256 + threadIdx.x;     // 8192 total
    int b = idx >> 9, n = idx & 511;
    const float* sr = S + n * 512;
    const float* st = state + b * 512;
    float acc = 0.f;
    for (int m2 = 0; m2 < 512; ++m2) acc += sr[m2] * st[m2];
    w0[idx] = acc;
  }
}

// ------- kC: lanczos (0..31) || GEMM1 (32..2079) || [split] Y2 (2080..4127)
// Lanczos block b owns rows [32b,32b+32) of G in VGPRs. Per iteration:
// publish 32 y-values as self-tagged 8B records {f32,iter} (one agent leg),
// poll all 1024, then redundantly+deterministically compute alpha,w,beta in
// every block (identical FP order => identical results). Block 0 keeps
// alpha/beta^2 in LDS and runs Sturm bisection + coef at the end.
// GEMM1 and Y2 share the SAME gemm_body<u16,0> instantiation + one LDS buf.
__global__ __launch_bounds__(256, 1) void kC(const float* __restrict__ G,
    u64* rec, const float* rho_raw, const float* theta, const float* log_gamma,
    float* scal, float2* coef,
    const u16* Xu, const u16* W12, u16* Bu, const u16* K22bf, u16* Y2bf){
  __shared__ __align__(16) u16 smA[128 * 64];
  __shared__ __align__(16) u16 smB[128 * 64];
  if (blockIdx.x >= LBLK + 2048){
    // Y2 = bf16(u_bf16 @ K22^T) -> workspace
    gemm_body<u16, 0>(blockIdx.x - LBLK - 2048, 2048, Xu, 1024, K22bf, 512,
                      Y2bf, 512, 512, 4, nullptr, nullptr, smA, smB);
    return;
  }
  if (blockIdx.x >= LBLK){
    gemm_body<u16, 0>(blockIdx.x - LBLK, 2048, Xu, 1024, W12, 512, Bu, 512,
                      512, 4, nullptr, nullptr, smA, smB);
    return;
  }
  __shared__ __align__(16) float vl[1024];  // raw v_{j-1} (full vector)
  __shared__ float red[8];
  __shared__ double sa[LM], sb2[LM + 1];
  __shared__ float sh_inv;
  int t = threadIdx.x, wave = t >> 6, lane = t & 63;
  int row0 = blockIdx.x * 32;

  // ---- my 32 G rows -> registers. wave w owns rows 8w..8w+7; lane l holds
  // floats [4l+256*i2, +4) of each row.
  f32x4 greg[8][4];
  {
    const float* gbase = G + (size_t)(row0 + wave * 8) * 1024 + lane * 4;
    #pragma unroll
    for (int rr = 0; rr < 8; ++rr)
      #pragma unroll
      for (int i2 = 0; i2 < 4; ++i2)
        greg[rr][i2] = *(const f32x4*)(gbase + (size_t)rr * 1024 + i2 * 256);
  }

  // ---- v0 raw + deterministic redundant norm (identical in every block)
  float vprevreg[4] = {0.f, 0.f, 0.f, 0.f};
  float n2tot;
  {
    float s = 0.f;
    #pragma unroll
    for (int k = 0; k < 4; ++k){
      int i = t + 256 * k;
      float v = sinf(0.613f * (float)i + 0.271f) + 0.3f * sinf(0.0247f * (float)i + 1.3f);
      vl[i] = v;
      s += v * v;
    }
    #pragma unroll
    for (int off = 32; off; off >>= 1) s += __shfl_down(s, off);
    if (lane == 0) red[wave] = s;
    __syncthreads();
    n2tot = (red[0] + red[1]) + (red[2] + red[3]);
  }
  float scl = 1.f / sqrtf(n2tot);      // 1/beta_0
  float betacoef = 0.f;                // no v_prev term at j=1
  if (t == 0) sb2[0] = 0.0;

  for (int j = 1; j <= LM; ++j){
    u64* rb = rec + ((j & 1) ? 0 : 1024);   // double buffer by parity
    // ---- y_raw(my rows) = G * v_raw; butterfly reduce so lanes 0..7 hold
    // their row's value; publish self-tagged records.
    {
      f32x4 vreg[4];
      #pragma unroll
      for (int i2 = 0; i2 < 4; ++i2)
        vreg[i2] = *((const f32x4*)vl + lane + 64 * i2);
      u64 myrec = 0ull;
      #pragma unroll
      for (int rr = 0; rr < 8; ++rr){
        float s = 0.f;
        #pragma unroll
        for (int i2 = 0; i2 < 4; ++i2){
          f32x4 g = greg[rr][i2], v = vreg[i2];
          s += g[0] * v[0] + g[1] * v[1] + g[2] * v[2] + g[3] * v[3];
        }
        #pragma unroll
        for (int off = 32; off; off >>= 1) s += __shfl_xor(s, off);
        if (lane == rr)
          myrec = ((u64)(u32)j << 32) | (u64)__float_as_uint(s);
      }
      if (lane < 8)
        __hip_atomic_store(&rb[row0 + wave * 8 + lane], myrec,
                           __ATOMIC_RELAXED, __HIP_MEMORY_SCOPE_AGENT);
    }

    // ---- poll full y: tag==j => payload valid. 4 loads kept in flight.
    float yr[4], vr[4];
    {
      u64 r0, r1, r2, r3;
      bool done = false;
      while (!done){
        r0 = __hip_atomic_load(&rb[t        ], __ATOMIC_RELAXED, __HIP_MEMORY_SCOPE_AGENT);
        r1 = __hip_atomic_load(&rb[t +  256 ], __ATOMIC_RELAXED, __HIP_MEMORY_SCOPE_AGENT);
        r2 = __hip_atomic_load(&rb[t +  512 ], __ATOMIC_RELAXED, __HIP_MEMORY_SCOPE_AGENT);
        r3 = __hip_atomic_load(&rb[t +  768 ], __ATOMIC_RELAXED, __HIP_MEMORY_SCOPE_AGENT);
        done = ((u32)(r0 >> 32) == (u32)j) && ((u32)(r1 >> 32) == (u32)j)
            && ((u32)(r2 >> 32) == (u32)j) && ((u32)(r3 >> 32) == (u32)j);
        if (!done) __builtin_amdgcn_s_sleep(1);
      }
      yr[0] = __uint_as_float((u32)r0); yr[1] = __uint_as_float((u32)r1);
      yr[2] = __uint_as_float((u32)r2); yr[3] = __uint_as_float((u32)r3);
      #pragma unroll
      for (int k = 0; k < 4; ++k) vr[k] = vl[t + 256 * k];
    }

    // ---- redundant deterministic alpha: dot = v_raw^T y_raw
    float dotp = 0.f;
    #pragma unroll
    for (int k = 0; k < 4; ++k) dotp += vr[k] * yr[k];
    #pragma unroll
    for (int off = 32; off; off >>= 1) dotp += __shfl_down(dotp, off);
    if (lane == 0) red[wave] = dotp;
    __syncthreads();
    float dot = (red[0] + red[1]) + (red[2] + red[3]);
    float alpha_f = dot * scl * scl;

    // ---- w = scl*y - alpha*vhat - beta*vprevhat (full vector, redundant)
    float n2 = 0.f;
    #pragma unroll
    for (int k = 0; k < 4; ++k){
      float vh = vr[k] * scl;
      float wv = yr[k] * scl - alpha_f * vh - betacoef * vprevreg[k];
      vprevreg[k] = vh;
      vl[t + 256 * k] = wv;            // raw next v
      n2 += wv * wv;
    }
    #pragma unroll
    for (int off = 32; off; off >>= 1) n2 += __shfl_down(n2, off);
    if (lane == 0) red[4 + wave] = n2;
    __syncthreads();                    // also orders vl[] writes vs next matvec
    n2tot = (red[4] + red[5]) + (red[6] + red[7]);
    if (n2tot < 1e-30f) n2tot = 1e-30f;

    if (t == 0){ sa[j - 1] = (double)alpha_f; sb2[j] = (double)n2tot; }
    betacoef = sqrtf(n2tot);
    scl = 1.f / betacoef;
  }

  // ---- block 0 tail: Sturm bisection for lambda_max(T), sigma, scan coef
  if (blockIdx.x != 0) return;
  __syncthreads();
  if (t < 64){
    int lane2 = t;
    double lo = sa[0], hi = sa[0], bmax = 0.0;
    for (int i = 0; i < LM; ++i){
      if (sa[i] > lo) lo = sa[i];
      double bl = (i > 0) ? sqrt(fmax(sb2[i], 0.0)) : 0.0;
      double br = (i < LM - 1) ? sqrt(fmax(sb2[i + 1], 0.0)) : 0.0;
      double g = sa[i] + bl + br;
      if (g > hi) hi = g;
      if (i < LM - 1 && sb2[i + 1] > bmax) bmax = sb2[i + 1];
    }
    hi = hi + 1e-6 * fabs(hi) + 1e-20;
    lo = lo - 1e-6 * fabs(lo) - 1e-20;
    double pivmin = 1e-30 * bmax + 1e-300;
    for (int round = 0; round < 6; ++round){
      double x = lo + (hi - lo) * ((double)(lane2 + 1) / 65.0);
      double d = sa[0] - x; int cnt = (d < 0.0);
      for (int i = 1; i < LM; ++i){
        if (fabs(d) < pivmin) d = -pivmin;
        d = (sa[i] - x) - sb2[i] / d;
        cnt += (d < 0.0);
      }
      unsigned long long mk = __ballot(cnt >= LM);
      int bpos = (mk == 0ULL) ? 64 : (__ffsll((unsigned long long)mk) - 1);
      double xlo = __shfl(x, (bpos == 0) ? 0 : bpos - 1);
      double xhi = __shfl(x, (bpos == 64) ? 63 : bpos);
      double nlo = (bpos == 0) ? lo : xlo;
      double nhi = (bpos == 64) ? hi : xhi;
      lo = nlo; hi = nhi;
    }
    if (lane2 == 0){
      double lam = 0.5 * (lo + hi);
      double sig = (lam > 0.0) ? sqrt(lam) : 0.0;
      if (sig < 1e-5) sig = 1e-5;
      double spp = sig + 0.002;
      float inv = (float)(1.0 / spp);
      float g = expf(log_gamma[0]);
      scal[0] = inv; scal[1] = g; scal[2] = g * inv;
      sh_inv = inv;
    }
  }
  __syncthreads();
  float inv = sh_inv;
  float rho = (1.f / (1.f + expf(-rho_raw[t]))) * 0.999f;
  float c = cosf(theta[t]), s = sinf(theta[t]);
  coef[t] = make_float2(rho * c * inv, rho * s * inv);
}

// ------------------------------ kD: scan (blocks 0..511) || wcat (512..)
// wcols = 512 (split: K21*inv only) or 1024 (fallback: [K21*inv | K22*gi])
__global__ __launch_bounds__(256) void kD(const u32* Bu, const float2* coef,
    const float* w0, const float* scal, u16* X,
    const float* K21, const float* K22, u16* W, int wcols){
  int blk = blockIdx.x;
  if (blk >= 512){
    int idx = (blk - 512) * 256 + threadIdx.x;
    float inv = scal[0], gi2 = scal[2];
    if (wcols == 1024){
      int o = idx >> 10, c = idx & 1023;
      float v = (c < 512) ? K21[o * 512 + c] * inv : K22[o * 512 + (c - 512)] * gi2;
      W[idx] = f2bf(v);
    } else {
      int o = idx >> 9, c = idx & 511;
      W[idx] = f2bf(K21[o * 512 + c] * inv);
    }
    return;
  }
  int b = blk >> 5;                  // 16 batches
  int c = blk & 31;                  // 32 chunks of 128
  int p = threadIdx.x;               // 256 pairs
  float2 ab = coef[p];
  float gi = scal[2];
  int t0 = c * CHUNK;
  float wx, wy; int t;
  if (c == 0){ wx = w0[b * 512 + 2 * p]; wy = w0[b * 512 + 2 * p + 1]; t = 0; }
  else { wx = 0.f; wy = 0.f; t = t0 - WARM; }
  const u32* bub = Bu + (size_t)b * 4096 * 256;
  u16* xb = X + (size_t)b * 4096 * 1024;
  for (; t < t0; ++t){
    u32 v = bub[(size_t)t * 256 + p];
    float bx = __uint_as_float(v << 16);
    float by = __uint_as_float(v & 0xffff0000u);
    float nx = ab.x * wx - ab.y * wy + gi * bx;
    float ny = ab.y * wx + ab.x * wy + gi * by;
    wx = nx; wy = ny;
  }
  for (; t < t0 + CHUNK; ++t){
    u32 pk = (u32)f2bf(wx) | ((u32)f2bf(wy) << 16);
    *(u32*)(xb + (size_t)t * 1024 + 2 * p) = pk;
    u32 v = bub[(size_t)t * 256 + p];
    float bx = __uint_as_float(v << 16);
    float by = __uint_as_float(v & 0xffff0000u);
    float nx = ab.x * wx - ab.y * wy + gi * bx;
    float ny = ab.y * wx + ab.x * wy + gi * by;
    wx = nx; wy = ny;
  }
}

// standalone GEMM wrapper (GEMM2 variants)
template <typename OT, int MODE>
__global__ __launch_bounds__(256) void gemm_nt(const u16* __restrict__ A, int lda,
    const u16* __restrict__ B, int ldb, OT* __restrict__ C, int ldc, int K,
    int ntn, const float* accs, const u16* __restrict__ Y2){
  __shared__ __align__(16) u16 smA[128 * 64];
  __shared__ __align__(16) u16 smB[128 * 64];
  gemm_body<OT, MODE>(blockIdx.x, gridDim.x, A, lda, B, ldb, C, ldc, K, ntn,
                      accs, Y2, smA, smB);
}

// ------------------------------------------------------------------- launcher
extern "C" void kernel_launch(void* const* d_in, const int* in_sizes, int n_in,
                              void* d_out, int out_size, void* d_ws, size_t ws_size,
                              hipStream_t stream){
  const float* u        = (const float*)d_in[0];
  const float* state    = (const float*)d_in[1];
  const float* S        = (const float*)d_in[2];
  const float* rho_raw  = (const float*)d_in[3];
  const float* theta    = (const float*)d_in[4];
  const float* K12      = (const float*)d_in[5];
  const float* K21      = (const float*)d_in[6];
  const float* K22      = (const float*)d_in[7];
  const float* log_gamma= (const float*)d_in[8];

  char* w = (char*)d_ws;
  size_t off = 0;
  auto alloc = [&](size_t bytes)->void*{
    void* p = w + off;
    off = (off + bytes + 255) & ~(size_t)255;
    return p;
  };
  u64*    rec   = (u64*)alloc(2048 * 8);       // 2 x 1024 self-tagged records
  float*  scal  = (float*)alloc(64);
  float2* coef  = (float2*)alloc(256 * 8);
  float*  w0    = (float*)alloc(16 * 512 * 4);
  u16*    KTbf  = (u16*)alloc((size_t)1024 * 1024 * 2);
  float*  G     = (float*)alloc((size_t)1024 * 1024 * 4);
  u16*    W12   = (u16*)alloc((size_t)512 * 512 * 2);
  u16*    K22bf = (u16*)alloc((size_t)512 * 512 * 2);
  u16*    Wcat  = (u16*)alloc((size_t)512 * 1024 * 2);
  u16*    Xb    = (u16*)alloc((size_t)65536 * 1024 * 2);
  u16*    BuWs  = (u16*)alloc((size_t)65536 * 512 * 2);   // split-mode Bu
  u16*    Y2bf  = (u16*)alloc((size_t)65536 * 512 * 2);   // split-mode Y2 (bf16)
  bool split = (off <= ws_size);
  // split: Bu+Y2 in ws, GEMM2 K=512 with epilogue add of gi*Y2.
  // fallback (ws too small): Bu aliases d_out, GEMM2 K=1024 (round-4 path).
  u16*    Bu    = split ? BuWs : (u16*)d_out;

  // kA: KT (4096) + conv_w12 (256) + conv_K22 (256) + rec init (1)
  kA<<<4609, 256, 0, stream>>>(rho_raw, theta, K12, K21, K22, KTbf,
                               (const float4*)K12, W12,
                               (const float4*)K22, K22bf, rec);
  // kB: G = KT @ KT^T (64, first) || conv_u (32768) || w0 (32)
  kB<<<32864, 256, 0, stream>>>(KTbf, G, (const float4*)u, Xb, S, state, w0);
  // kC: lanczos+finalize (32, first) || GEMM1 (2048) || [split] Y2 (2048)
  kC<<<LBLK + 2048 + (split ? 2048 : 0), 256, 0, stream>>>(
      G, rec, rho_raw, theta, log_gamma, scal, coef,
      Xb + 512, W12, Bu, K22bf, Y2bf);
  // kD: scan (512, first) || build_wcat
  kD<<<512 + (split ? 1024 : 2048), 256, 0, stream>>>(
      (const u32*)Bu, coef, w0, scal, Xb, K21, K22, Wcat, split ? 512 : 1024);
  if (split){
    // GEMM2: y = pre @ (K21*inv)^T + gi * Y2   (K=512, hoisted-load epilogue)
    gemm_nt<float, 1><<<2048, 256, 0, stream>>>(Xb, 1024, Wcat, 512,
                                                (float*)d_out, 512, 512, 4,
                                                scal, Y2bf);
  } else {
    // GEMM2: y = [pre|u] @ [K21n | gamma*K22n]^T  (K=1024)
    gemm_nt<float, 0><<<2048, 256, 0, stream>>>(Xb, 1024, Wcat, 1024,
                                                (float*)d_out, 512, 1024, 4,
                                                nullptr, nullptr);
  }
}

// Round 7
// 557.568 us; speedup vs baseline: 1.1541x; 1.0106x over previous
//
#include <hip/hip_runtime.h>
#include <stdint.h>

// ---------------------------------------------------------------------------
// SSL_34857954574989: dense SSM with spectral-norm-scaled K.
// w = S x  =>  w_{t+1} = K11n w_t + gamma*K12n u_t ;  y_t = K21n w_t + gamma*K22n u_t
//
// 4 launches (role-split by blockIdx; no resident role waits on a starvable
// producer -> deadlock-free regardless of dispatch order):
//  kA: build_KT(bf16) + conv_w12 + rec/flag init + conv_u + w0_matvec
//  kC: G = K^T K (64 blocks, agent-atomic C stores + done-counter)
//      || 40-step Lanczos (32 blocks; poll counter, load G rows to VGPRs;
//         self-tagged 8B record exchange, one leg/iter; alpha/beta
//         redundant+deterministic; Sturm + scan-coef in first lanczos block)
//      || GEMM1 (Bu = u @ K12^T, 2048 blocks, sigma-independent -> hidden
//         under lanczos latency)
//  kD: scan (512 blocks, first) || build_wcat
//  GEMM2: y = [pre|u] @ [K21n | gamma*K22n]^T  (K=1024)
// Bu (bf16, 64 MB) aliases d_out; consumed by scan before GEMM2 overwrites.
// ---------------------------------------------------------------------------

#define LM 40            // Lanczos steps
#define CHUNK 128        // scan chunk length
#define WARM 12          // scan warm-up steps
#define LBLK 32          // lanczos blocks (32 rows each)

typedef float f32x4 __attribute__((ext_vector_type(4)));
typedef __bf16 bf16x8 __attribute__((ext_vector_type(8)));
typedef unsigned int u32;
typedef unsigned long long u64;
typedef unsigned short u16;

static __device__ __forceinline__ u16 f2bf(float f){
  u32 u = __float_as_uint(f);
  u32 r = (u + 0x7fffu + ((u >> 16) & 1u)) >> 16;
  return (u16)r;
}

// K_raw(i,j) evaluated directly (i=row, j=col of the 1024x1024 block matrix)
static __device__ __forceinline__ float kraw_at(int i, int j,
    const float* rho_raw, const float* theta,
    const float* K12, const float* K21, const float* K22){
  if (i < 512){
    if (j < 512){
      if ((i >> 1) != (j >> 1)) return 0.f;
      int p = i >> 1;
      float rho = (1.f / (1.f + expf(-rho_raw[p]))) * 0.999f;
      float c = cosf(theta[p]), s = sinf(theta[p]);
      return ((i & 1) == 0) ? (((j & 1) == 0) ? rho * c : -rho * s)
                            : (((j & 1) == 0) ? rho * s :  rho * c);
    }
    return K12[i * 512 + (j - 512)];
  }
  if (j < 512) return K21[(i - 512) * 512 + j];
  return K22[(i - 512) * 512 + (j - 512)];
}

// ------------------------------------------------------------------ bf16 GEMM
// C[M x N] = A[M x K] bf16 * B[N x K]^T bf16. 128x128 tile, BK=64.
// XCD-partitioned block swizzle; XOR-swizzled LDS layout. LDS caller-provided
// (32 KB) so multiple roles in one kernel share one allocation.
// MODE 0: plain store (float or bf16). MODE 2: f32 agent-scope atomic store
// (for same-kernel consumers on other XCDs).
static __device__ __forceinline__ void gload16(const u16* g, u16* l){
  __builtin_amdgcn_global_load_lds((const __attribute__((address_space(1))) u32*)g,
                                   (__attribute__((address_space(3))) u32*)l, 16, 0, 0);
}

template <typename OT, int MODE>
static __device__ __forceinline__ void gemm_body(int g, int ngrid,
    const u16* __restrict__ A, int lda, const u16* __restrict__ B, int ldb,
    OT* __restrict__ C, int ldc, int K, int ntn, u16* As, u16* Bs){
  int xcd = g & 7, local = g >> 3;
  int mper = (ngrid >> 3) / ntn;              // m-tiles per xcd
  int bn = local % ntn;
  int bm = xcd * mper + local / ntn;
  int t = threadIdx.x, lane = t & 63, wave = t >> 6;
  int lrow = t >> 3;                          // 0..31
  int swz = (((t & 7) ^ (lrow & 7)) << 3);    // XOR-swizzled col offset (elems)
  const u16* Ag = A + (size_t)(bm * 128 + lrow) * lda + swz;
  const u16* Bg = B + (size_t)(bn * 128 + lrow) * ldb + swz;
  u16* Asd = As + t * 8;
  u16* Bsd = Bs + t * 8;
  f32x4 acc[4][4];
  #pragma unroll
  for (int mi = 0; mi < 4; ++mi)
    #pragma unroll
    for (int ni = 0; ni < 4; ++ni) acc[mi][ni] = (f32x4){0.f, 0.f, 0.f, 0.f};
  int wm = (wave & 1) << 6, wn = (wave >> 1) << 6;
  int fr = lane & 15, cbb = lane >> 4;
  for (int kt = 0; kt < K; kt += 64){
    __syncthreads();
    #pragma unroll
    for (int r = 0; r < 4; ++r){
      gload16(Ag + (size_t)(r * 32) * lda + kt, Asd + r * 2048);
      gload16(Bg + (size_t)(r * 32) * ldb + kt, Bsd + r * 2048);
    }
    __syncthreads();
    #pragma unroll
    for (int kk = 0; kk < 2; ++kk){
      bf16x8 af[4], bfr[4];
      #pragma unroll
      for (int mi = 0; mi < 4; ++mi){
        int row = wm + mi * 16 + fr;
        int pcb = ((kk << 2) + cbb) ^ (fr & 7);
        af[mi] = *(const bf16x8*)(As + row * 64 + pcb * 8);
      }
      #pragma unroll
      for (int ni = 0; ni < 4; ++ni){
        int row = wn + ni * 16 + fr;
        int pcb = ((kk << 2) + cbb) ^ (fr & 7);
        bfr[ni] = *(const bf16x8*)(Bs + row * 64 + pcb * 8);
      }
      #pragma unroll
      for (int mi = 0; mi < 4; ++mi)
        #pragma unroll
        for (int ni = 0; ni < 4; ++ni)
          acc[mi][ni] = __builtin_amdgcn_mfma_f32_16x16x32_bf16(af[mi], bfr[ni], acc[mi][ni], 0, 0, 0);
    }
  }
  int rq = lane >> 4;
  #pragma unroll
  for (int mi = 0; mi < 4; ++mi)
    #pragma unroll
    for (int ni = 0; ni < 4; ++ni){
      size_t base = (size_t)(bm * 128 + wm + mi * 16 + rq * 4) * ldc
                  + (size_t)(bn * 128 + wn + ni * 16 + fr);
      #pragma unroll
      for (int r = 0; r < 4; ++r){
        size_t idx = base + (size_t)r * ldc;
        if constexpr (MODE == 2){
          __hip_atomic_store((float*)&C[idx], acc[mi][ni][r],
                             __ATOMIC_RELAXED, __HIP_MEMORY_SCOPE_AGENT);
        } else if constexpr (sizeof(OT) == 4){
          C[idx] = acc[mi][ni][r];
        } else {
          C[idx] = (OT)f2bf(acc[mi][ni][r]);
        }
      }
    }
}

// ---- kA: KT (0..4095) + conv_w12 (4096..4351) + init (4352)
//        + conv_u (4353..37120) + w0 (37121..37152)
__global__ __launch_bounds__(256) void kA(const float* rho_raw, const float* theta,
    const float* K12, const float* K21, const float* K22, u16* KTbf,
    const float4* k12_4, u16* W12, u64* rec, u32* gflag,
    const float4* u4, u16* X, const float* S, const float* state, float* w0){
  int blk = blockIdx.x;
  int t = threadIdx.x;
  if (blk < 4096){
    int idx = blk * 256 + t;                     // KT output idx
    int j = idx >> 10, i = idx & 1023;           // KT row j, col i
    KTbf[idx] = f2bf(kraw_at(i, j, rho_raw, theta, K12, K21, K22));
  } else if (blk < 4352){
    long g = (long)(blk - 4096) * 256 + t;       // 65536 total
    float4 v = k12_4[g];
    u32 lo = (u32)f2bf(v.x) | ((u32)f2bf(v.y) << 16);
    u32 hi = (u32)f2bf(v.z) | ((u32)f2bf(v.w) << 16);
    ((uint2*)W12)[g] = make_uint2(lo, hi);
  } else if (blk == 4352){
    for (int i = t; i < 2048; i += 256) rec[i] = 0ull;
    if (t == 0) gflag[0] = 0u;
  } else if (blk < 4353 + 32768){
    long g = (long)(blk - 4353) * 256 + t;       // 8388608 total
    float4 v = u4[g];
    int h4 = (int)(g & 127);
    long row = g >> 7;
    u16* dst = X + row * 1024 + 512 + h4 * 4;
    u32 lo = (u32)f2bf(v.x) | ((u32)f2bf(v.y) << 16);
    u32 hi = (u32)f2bf(v.z) | ((u32)f2bf(v.w) << 16);
    *((uint2*)dst) = make_uint2(lo, hi);
  } else {
    int idx = (blk - 37121) * 256 + t;           // 8192 total
    int b = idx >> 9, n = idx & 511;
    const float* sr = S + n * 512;
    const float* st = state + b * 512;
    float acc = 0.f;
    for (int m2 = 0; m2 < 512; ++m2) acc += sr[m2] * st[m2];
    w0[idx] = acc;
  }
}

// ---- kC: Ggemm (0..63, atomic stores + counter) || lanczos (64..95, polls
//          counter) || GEMM1 (96..2143)
// Lanczos block b owns G rows [32b,32b+32) in VGPRs. Per iteration: publish
// 32 y-values as self-tagged 8B records {f32,iter} (one agent leg), poll all
// 1024, then redundantly+deterministically compute alpha,w,beta in every
// block (identical FP order => identical results). First lanczos block keeps
// alpha/beta^2 in LDS and runs Sturm bisection + coef at the end.
__global__ __launch_bounds__(256, 1) void kC(const u16* __restrict__ KTbf,
    float* G, u32* gflag, u64* rec,
    const float* rho_raw, const float* theta, const float* log_gamma,
    float* scal, float2* coef,
    const u16* Xu, const u16* W12, u16* Bu){
  __shared__ __align__(16) u16 smA[128 * 64];
  __shared__ __align__(16) u16 smB[128 * 64];
  int blk = blockIdx.x;
  if (blk < 64){
    // G = KT @ KT^T with agent-visible stores; then bump done-counter.
    gemm_body<float, 2>(blk, 64, KTbf, 1024, KTbf, 1024, G, 1024, 1024, 8,
                        smA, smB);
    asm volatile("s_waitcnt vmcnt(0)" ::: "memory");
    __syncthreads();
    if (threadIdx.x == 0)
      __hip_atomic_fetch_add(gflag, 1u, __ATOMIC_RELAXED, __HIP_MEMORY_SCOPE_AGENT);
    return;
  }
  if (blk >= 64 + LBLK){
    gemm_body<u16, 0>(blk - 64 - LBLK, 2048, Xu, 1024, W12, 512, Bu, 512,
                      512, 4, smA, smB);
    return;
  }
  __shared__ __align__(16) float vl[1024];  // raw v_{j-1} (full vector)
  __shared__ float red[8];
  __shared__ double sa[LM], sb2[LM + 1];
  __shared__ float sh_inv;
  int t = threadIdx.x, wave = t >> 6, lane = t & 63;
  int row0 = (blk - 64) * 32;

  // ---- wait for G to be fully written (agent-atomic stores are L3-visible;
  // our L2 has no stale copy of G this kernel -> clean miss -> correct data)
  if (t == 0){
    while (__hip_atomic_load(gflag, __ATOMIC_RELAXED, __HIP_MEMORY_SCOPE_AGENT) < 64u)
      __builtin_amdgcn_s_sleep(2);
  }
  __syncthreads();

  // ---- my 32 G rows -> registers. wave w owns rows 8w..8w+7; lane l holds
  // floats [4l+256*i2, +4) of each row.
  f32x4 greg[8][4];
  {
    const float* gbase = G + (size_t)(row0 + wave * 8) * 1024 + lane * 4;
    #pragma unroll
    for (int rr = 0; rr < 8; ++rr)
      #pragma unroll
      for (int i2 = 0; i2 < 4; ++i2)
        greg[rr][i2] = *(const f32x4*)(gbase + (size_t)rr * 1024 + i2 * 256);
  }

  // ---- v0 raw + deterministic redundant norm (identical in every block)
  float vprevreg[4] = {0.f, 0.f, 0.f, 0.f};
  float n2tot;
  {
    float s = 0.f;
    #pragma unroll
    for (int k = 0; k < 4; ++k){
      int i = t + 256 * k;
      float v = sinf(0.613f * (float)i + 0.271f) + 0.3f * sinf(0.0247f * (float)i + 1.3f);
      vl[i] = v;
      s += v * v;
    }
    #pragma unroll
    for (int off = 32; off; off >>= 1) s += __shfl_down(s, off);
    if (lane == 0) red[wave] = s;
    __syncthreads();
    n2tot = (red[0] + red[1]) + (red[2] + red[3]);
  }
  float scl = 1.f / sqrtf(n2tot);      // 1/beta_0
  float betacoef = 0.f;                // no v_prev term at j=1
  if (t == 0) sb2[0] = 0.0;

  for (int j = 1; j <= LM; ++j){
    u64* rb = rec + ((j & 1) ? 0 : 1024);   // double buffer by parity
    // ---- y_raw(my rows) = G * v_raw; butterfly reduce so lanes 0..7 hold
    // their row's value; publish self-tagged records.
    {
      f32x4 vreg[4];
      #pragma unroll
      for (int i2 = 0; i2 < 4; ++i2)
        vreg[i2] = *((const f32x4*)vl + lane + 64 * i2);
      u64 myrec = 0ull;
      #pragma unroll
      for (int rr = 0; rr < 8; ++rr){
        float s = 0.f;
        #pragma unroll
        for (int i2 = 0; i2 < 4; ++i2){
          f32x4 g = greg[rr][i2], v = vreg[i2];
          s += g[0] * v[0] + g[1] * v[1] + g[2] * v[2] + g[3] * v[3];
        }
        #pragma unroll
        for (int off = 32; off; off >>= 1) s += __shfl_xor(s, off);
        if (lane == rr)
          myrec = ((u64)(u32)j << 32) | (u64)__float_as_uint(s);
      }
      if (lane < 8)
        __hip_atomic_store(&rb[row0 + wave * 8 + lane], myrec,
                           __ATOMIC_RELAXED, __HIP_MEMORY_SCOPE_AGENT);
    }

    // ---- poll full y: tag==j => payload valid. 4 loads kept in flight.
    float yr[4], vr[4];
    {
      u64 r0, r1, r2, r3;
      bool done = false;
      while (!done){
        r0 = __hip_atomic_load(&rb[t        ], __ATOMIC_RELAXED, __HIP_MEMORY_SCOPE_AGENT);
        r1 = __hip_atomic_load(&rb[t +  256 ], __ATOMIC_RELAXED, __HIP_MEMORY_SCOPE_AGENT);
        r2 = __hip_atomic_load(&rb[t +  512 ], __ATOMIC_RELAXED, __HIP_MEMORY_SCOPE_AGENT);
        r3 = __hip_atomic_load(&rb[t +  768 ], __ATOMIC_RELAXED, __HIP_MEMORY_SCOPE_AGENT);
        done = ((u32)(r0 >> 32) == (u32)j) && ((u32)(r1 >> 32) == (u32)j)
            && ((u32)(r2 >> 32) == (u32)j) && ((u32)(r3 >> 32) == (u32)j);
        if (!done) __builtin_amdgcn_s_sleep(1);
      }
      yr[0] = __uint_as_float((u32)r0); yr[1] = __uint_as_float((u32)r1);
      yr[2] = __uint_as_float((u32)r2); yr[3] = __uint_as_float((u32)r3);
      #pragma unroll
      for (int k = 0; k < 4; ++k) vr[k] = vl[t + 256 * k];
    }

    // ---- redundant deterministic alpha: dot = v_raw^T y_raw
    float dotp = 0.f;
    #pragma unroll
    for (int k = 0; k < 4; ++k) dotp += vr[k] * yr[k];
    #pragma unroll
    for (int off = 32; off; off >>= 1) dotp += __shfl_down(dotp, off);
    if (lane == 0) red[wave] = dotp;
    __syncthreads();
    float dot = (red[0] + red[1]) + (red[2] + red[3]);
    float alpha_f = dot * scl * scl;

    // ---- w = scl*y - alpha*vhat - beta*vprevhat (full vector, redundant)
    float n2 = 0.f;
    #pragma unroll
    for (int k = 0; k < 4; ++k){
      float vh = vr[k] * scl;
      float wv = yr[k] * scl - alpha_f * vh - betacoef * vprevreg[k];
      vprevreg[k] = vh;
      vl[t + 256 * k] = wv;            // raw next v
      n2 += wv * wv;
    }
    #pragma unroll
    for (int off = 32; off; off >>= 1) n2 += __shfl_down(n2, off);
    if (lane == 0) red[4 + wave] = n2;
    __syncthreads();                    // also orders vl[] writes vs next matvec
    n2tot = (red[4] + red[5]) + (red[6] + red[7]);
    if (n2tot < 1e-30f) n2tot = 1e-30f;

    if (t == 0){ sa[j - 1] = (double)alpha_f; sb2[j] = (double)n2tot; }
    betacoef = sqrtf(n2tot);
    scl = 1.f / betacoef;
  }

  // ---- first lanczos block tail: Sturm bisection, sigma, scan coef
  if (blk != 64) return;
  __syncthreads();
  if (t < 64){
    int lane2 = t;
    double lo = sa[0], hi = sa[0], bmax = 0.0;
    for (int i = 0; i < LM; ++i){
      if (sa[i] > lo) lo = sa[i];
      double bl = (i > 0) ? sqrt(fmax(sb2[i], 0.0)) : 0.0;
      double br = (i < LM - 1) ? sqrt(fmax(sb2[i + 1], 0.0)) : 0.0;
      double g = sa[i] + bl + br;
      if (g > hi) hi = g;
      if (i < LM - 1 && sb2[i + 1] > bmax) bmax = sb2[i + 1];
    }
    hi = hi + 1e-6 * fabs(hi) + 1e-20;
    lo = lo - 1e-6 * fabs(lo) - 1e-20;
    double pivmin = 1e-30 * bmax + 1e-300;
    for (int round = 0; round < 6; ++round){
      double x = lo + (hi - lo) * ((double)(lane2 + 1) / 65.0);
      double d = sa[0] - x; int cnt = (d < 0.0);
      for (int i = 1; i < LM; ++i){
        if (fabs(d) < pivmin) d = -pivmin;
        d = (sa[i] - x) - sb2[i] / d;
        cnt += (d < 0.0);
      }
      unsigned long long mk = __ballot(cnt >= LM);
      int bpos = (mk == 0ULL) ? 64 : (__ffsll((unsigned long long)mk) - 1);
      double xlo = __shfl(x, (bpos == 0) ? 0 : bpos - 1);
      double xhi = __shfl(x, (bpos == 64) ? 63 : bpos);
      double nlo = (bpos == 0) ? lo : xlo;
      double nhi = (bpos == 64) ? hi : xhi;
      lo = nlo; hi = nhi;
    }
    if (lane2 == 0){
      double lam = 0.5 * (lo + hi);
      double sig = (lam > 0.0) ? sqrt(lam) : 0.0;
      if (sig < 1e-5) sig = 1e-5;
      double spp = sig + 0.002;
      float inv = (float)(1.0 / spp);
      float g = expf(log_gamma[0]);
      scal[0] = inv; scal[1] = g; scal[2] = g * inv;
      sh_inv = inv;
    }
  }
  __syncthreads();
  float inv = sh_inv;
  float rho = (1.f / (1.f + expf(-rho_raw[t]))) * 0.999f;
  float c = cosf(theta[t]), s = sinf(theta[t]);
  coef[t] = make_float2(rho * c * inv, rho * s * inv);
}

// ------------------------------ kD: scan (blocks 0..511) || wcat (512..2559)
__global__ __launch_bounds__(256) void kD(const u32* Bu, const float2* coef,
    const float* w0, const float* scal, u16* X,
    const float* K21, const float* K22, u16* W){
  int blk = blockIdx.x;
  if (blk >= 512){
    int idx = (blk - 512) * 256 + threadIdx.x;       // 524288 total
    int o = idx >> 10, c = idx & 1023;
    float inv = scal[0], gi2 = scal[2];
    float v = (c < 512) ? K21[o * 512 + c] * inv : K22[o * 512 + (c - 512)] * gi2;
    W[idx] = f2bf(v);
    return;
  }
  int b = blk >> 5;                  // 16 batches
  int c = blk & 31;                  // 32 chunks of 128
  int p = threadIdx.x;               // 256 pairs
  float2 ab = coef[p];
  float gi = scal[2];
  int t0 = c * CHUNK;
  float wx, wy; int t;
  if (c == 0){ wx = w0[b * 512 + 2 * p]; wy = w0[b * 512 + 2 * p + 1]; t = 0; }
  else { wx = 0.f; wy = 0.f; t = t0 - WARM; }
  const u32* bub = Bu + (size_t)b * 4096 * 256;
  u16* xb = X + (size_t)b * 4096 * 1024;
  for (; t < t0; ++t){
    u32 v = bub[(size_t)t * 256 + p];
    float bx = __uint_as_float(v << 16);
    float by = __uint_as_float(v & 0xffff0000u);
    float nx = ab.x * wx - ab.y * wy + gi * bx;
    float ny = ab.y * wx + ab.x * wy + gi * by;
    wx = nx; wy = ny;
  }
  for (; t < t0 + CHUNK; ++t){
    u32 pk = (u32)f2bf(wx) | ((u32)f2bf(wy) << 16);
    *(u32*)(xb + (size_t)t * 1024 + 2 * p) = pk;
    u32 v = bub[(size_t)t * 256 + p];
    float bx = __uint_as_float(v << 16);
    float by = __uint_as_float(v & 0xffff0000u);
    float nx = ab.x * wx - ab.y * wy + gi * bx;
    float ny = ab.y * wx + ab.x * wy + gi * by;
    wx = nx; wy = ny;
  }
}

// standalone GEMM wrapper (GEMM2)
template <typename OT, int MODE>
__global__ __launch_bounds__(256) void gemm_nt(const u16* __restrict__ A, int lda,
    const u16* __restrict__ B, int ldb, OT* __restrict__ C, int ldc, int K, int ntn){
  __shared__ __align__(16) u16 smA[128 * 64];
  __shared__ __align__(16) u16 smB[128 * 64];
  gemm_body<OT, MODE>(blockIdx.x, gridDim.x, A, lda, B, ldb, C, ldc, K, ntn,
                      smA, smB);
}

// ------------------------------------------------------------------- launcher
extern "C" void kernel_launch(void* const* d_in, const int* in_sizes, int n_in,
                              void* d_out, int out_size, void* d_ws, size_t ws_size,
                              hipStream_t stream){
  const float* u        = (const float*)d_in[0];
  const float* state    = (const float*)d_in[1];
  const float* S        = (const float*)d_in[2];
  const float* rho_raw  = (const float*)d_in[3];
  const float* theta    = (const float*)d_in[4];
  const float* K12      = (const float*)d_in[5];
  const float* K21      = (const float*)d_in[6];
  const float* K22      = (const float*)d_in[7];
  const float* log_gamma= (const float*)d_in[8];

  char* w = (char*)d_ws;
  size_t off = 0;
  auto alloc = [&](size_t bytes)->void*{
    void* p = w + off;
    off = (off + bytes + 255) & ~(size_t)255;
    return p;
  };
  u64*    rec   = (u64*)alloc(2048 * 8);       // 2 x 1024 self-tagged records
  u32*    gflag = (u32*)alloc(256);            // G-GEMM done counter
  float*  scal  = (float*)alloc(64);
  float2* coef  = (float2*)alloc(256 * 8);
  float*  w0    = (float*)alloc(16 * 512 * 4);
  u16*    KTbf  = (u16*)alloc((size_t)1024 * 1024 * 2);
  float*  G     = (float*)alloc((size_t)1024 * 1024 * 4);
  u16*    W12   = (u16*)alloc((size_t)512 * 512 * 2);
  u16*    Wcat  = (u16*)alloc((size_t)512 * 1024 * 2);
  u16*    Xb    = (u16*)alloc((size_t)65536 * 1024 * 2);
  // Bu (bf16, 64 MB) aliases d_out; consumed by scan before GEMM2 overwrites.
  u16*    Bu    = (u16*)d_out;

  // kA: KT (4096) + conv_w12 (256) + init (1) + conv_u (32768) + w0 (32)
  kA<<<37153, 256, 0, stream>>>(rho_raw, theta, K12, K21, K22, KTbf,
                                (const float4*)K12, W12, rec, gflag,
                                (const float4*)u, Xb, S, state, w0);
  // kC: Ggemm (64) || lanczos+finalize (32) || GEMM1 Bu = u_bf16 @ K12^T (2048)
  kC<<<64 + LBLK + 2048, 256, 0, stream>>>(KTbf, G, gflag, rec,
                                           rho_raw, theta, log_gamma,
                                           scal, coef, Xb + 512, W12, Bu);
  // kD: scan (512, first) || build_wcat (2048)
  kD<<<2560, 256, 0, stream>>>((const u32*)Bu, coef, w0, scal, Xb, K21, K22, Wcat);
  // GEMM2: y = [pre|u] @ [K21n | gamma*K22n]^T  (M=65536, N=512, K=1024)
  gemm_nt<float, 0><<<2048, 256, 0, stream>>>(Xb, 1024, Wcat, 1024,
                                              (float*)d_out, 512, 1024, 4);
}